// Round 1
// baseline (1004.568 us; speedup 1.0000x reference)
//
#include <hip/hip_runtime.h>
#include <math.h>

#define B_ 8
#define T_ 2048
#define E_ 512
#define CCH 256
#define NC_ (T_ / CCH)          // 8 chunks
#define EPS_ 1e-3f
#define QSCALE 0.044194173824159216f   // 512^-0.5

// ---------------------------------------------------------------------------
// Kernel 1: projections.  out[b,t,i] = sum_e x[b,e,t] * W[i,e] + bias[i]
// mode 0: q raw; mode 1: k = exp(.); mode 2: v = (.) * toep[t]
// Tiles: 64 (t) x 64 (i), K-slice 16 over e. 256 threads, 4x4 per thread.
// ---------------------------------------------------------------------------
__global__ void proj_kernel(const float* __restrict__ x, const float* __restrict__ W,
                            const float* __restrict__ bias, const float* __restrict__ toep,
                            float* __restrict__ out, int mode) {
    __shared__ float As[16][64];   // [e_l][t]   (x is (E,T): t contiguous)
    __shared__ float Ws[16][68];   // [e_l][i]   (transposed load, padded)
    int tid = threadIdx.x;
    int tx = tid & 15, ty = tid >> 4;
    int t0 = blockIdx.x * 64;
    int i0 = blockIdx.y * 64;
    int b  = blockIdx.z;
    const float* xb = x + (size_t)b * E_ * T_;
    float acc[4][4] = {};
    for (int e0 = 0; e0 < E_; e0 += 16) {
        {
            int tt = tid & 63, el0 = tid >> 6;
            #pragma unroll
            for (int r = 0; r < 4; ++r) {
                int e_l = el0 + 4 * r;
                As[e_l][tt] = xb[(size_t)(e0 + e_l) * T_ + t0 + tt];
            }
        }
        {
            int e_l = tid & 15, il0 = tid >> 4;
            #pragma unroll
            for (int r = 0; r < 4; ++r) {
                int i_l = il0 + 16 * r;
                Ws[e_l][i_l] = W[(size_t)(i0 + i_l) * E_ + e0 + e_l];
            }
        }
        __syncthreads();
        #pragma unroll
        for (int kk = 0; kk < 16; ++kk) {
            float a[4], bb[4];
            #pragma unroll
            for (int r = 0; r < 4; ++r) a[r] = As[kk][ty * 4 + r];
            #pragma unroll
            for (int c = 0; c < 4; ++c) bb[c] = Ws[kk][tx * 4 + c];
            #pragma unroll
            for (int r = 0; r < 4; ++r)
                #pragma unroll
                for (int c = 0; c < 4; ++c) acc[r][c] += a[r] * bb[c];
        }
        __syncthreads();
    }
    #pragma unroll
    for (int r = 0; r < 4; ++r) {
        int t = t0 + ty * 4 + r;
        float tw = (mode == 2) ? toep[t] : 1.f;
        #pragma unroll
        for (int c = 0; c < 4; ++c) {
            int i = i0 + tx * 4 + c;
            float vv = acc[r][c] + bias[i];
            if (mode == 1) vv = expf(vv);
            if (mode == 2) vv = vv * tw;
            out[((size_t)b * T_ + t) * E_ + i] = vv;
        }
    }
}

// ---------------------------------------------------------------------------
// Kernel 2: in-place softmax over last dim (512) of q, then * E^-0.5
// ---------------------------------------------------------------------------
__global__ void softmax_kernel(float* __restrict__ q) {
    __shared__ float red[256];
    int row = blockIdx.x;
    float* p = q + (size_t)row * E_;
    int tid = threadIdx.x;
    float v0 = p[tid], v1 = p[tid + 256];
    red[tid] = fmaxf(v0, v1);
    __syncthreads();
    for (int s = 128; s > 0; s >>= 1) {
        if (tid < s) red[tid] = fmaxf(red[tid], red[tid + s]);
        __syncthreads();
    }
    float m = red[0];
    __syncthreads();
    float e0 = expf(v0 - m), e1 = expf(v1 - m);
    red[tid] = e0 + e1;
    __syncthreads();
    for (int s = 128; s > 0; s >>= 1) {
        if (tid < s) red[tid] += red[tid + s];
        __syncthreads();
    }
    float inv = QSCALE / red[0];
    p[tid] = e0 * inv;
    p[tid + 256] = e1 * inv;
}

// ---------------------------------------------------------------------------
// Kernel 3: per-chunk KV[bc, ek, ev] = sum_{t in chunk} k[t,ek] * v[t,ev]
// ---------------------------------------------------------------------------
__global__ void chunk_kv_kernel(const float* __restrict__ k, const float* __restrict__ v,
                                float* __restrict__ KV) {
    __shared__ float Ks[16][64];
    __shared__ float Vs[16][64];
    int tid = threadIdx.x;
    int tx = tid & 15, ty = tid >> 4;
    int ev0 = blockIdx.x * 64;
    int ek0 = blockIdx.y * 64;
    int bc = blockIdx.z;
    int b = bc / NC_, c = bc % NC_;
    size_t tbase = (size_t)b * T_ + (size_t)c * CCH;
    float acc[4][4] = {};
    for (int ts = 0; ts < CCH; ts += 16) {
        int j = tid & 63, tl0 = tid >> 6;
        #pragma unroll
        for (int r = 0; r < 4; ++r) {
            int tl = tl0 + 4 * r;
            Ks[tl][j] = k[(tbase + ts + tl) * E_ + ek0 + j];
            Vs[tl][j] = v[(tbase + ts + tl) * E_ + ev0 + j];
        }
        __syncthreads();
        #pragma unroll
        for (int kk = 0; kk < 16; ++kk) {
            float a[4], bb[4];
            #pragma unroll
            for (int r = 0; r < 4; ++r) a[r] = Ks[kk][ty * 4 + r];
            #pragma unroll
            for (int c2 = 0; c2 < 4; ++c2) bb[c2] = Vs[kk][tx * 4 + c2];
            #pragma unroll
            for (int r = 0; r < 4; ++r)
                #pragma unroll
                for (int c2 = 0; c2 < 4; ++c2) acc[r][c2] += a[r] * bb[c2];
        }
        __syncthreads();
    }
    #pragma unroll
    for (int r = 0; r < 4; ++r)
        #pragma unroll
        for (int c2 = 0; c2 < 4; ++c2)
            KV[((size_t)bc * E_ + ek0 + ty * 4 + r) * E_ + ev0 + tx * 4 + c2] = acc[r][c2];
}

// ---------------------------------------------------------------------------
// Kernel 4: per-chunk key sum
// ---------------------------------------------------------------------------
__global__ void ksum_kernel(const float* __restrict__ k, float* __restrict__ ks) {
    int bc = blockIdx.x;
    int b = bc / NC_, c = bc % NC_;
    int e = blockIdx.y * 256 + threadIdx.x;
    const float* kp = k + ((size_t)b * T_ + (size_t)c * CCH) * E_ + e;
    float s = 0.f;
    for (int t = 0; t < CCH; ++t) s += kp[(size_t)t * E_];
    ks[(size_t)bc * E_ + e] = s;
}

// ---------------------------------------------------------------------------
// Kernel 5: exclusive prefix scan over chunks, in place.
// buf layout (B, NC, nper); one thread per (b, idx).
// ---------------------------------------------------------------------------
__global__ void scan_kernel(float* __restrict__ buf, size_t nper) {
    size_t gid = (size_t)blockIdx.x * 256 + threadIdx.x;
    size_t b = gid / nper, idx = gid % nper;
    float run = 0.f;
    float* p = buf + b * NC_ * nper + idx;
    for (int c = 0; c < NC_; ++c) {
        float t = *p;
        *p = run;
        run += t;
        p += nper;
    }
}

// ---------------------------------------------------------------------------
// Kernel 6: P[bc, ti, tj] = (tj<=ti) ? sum_e q[ti,e]*k[tj,e] : 0   (intra-chunk)
// ---------------------------------------------------------------------------
__global__ void pmat_kernel(const float* __restrict__ q, const float* __restrict__ k,
                            float* __restrict__ P) {
    int tid = threadIdx.x;
    int tx = tid & 15, ty = tid >> 4;
    int tj0 = blockIdx.x * 64, ti0 = blockIdx.y * 64;
    int bc = blockIdx.z;
    int b = bc / NC_, c = bc % NC_;
    float* Pp = P + (size_t)bc * CCH * CCH;
    if (tj0 > ti0 + 63) {   // fully above diagonal: must still write (poison!)
        #pragma unroll
        for (int r = 0; r < 4; ++r)
            #pragma unroll
            for (int c2 = 0; c2 < 4; ++c2)
                Pp[(size_t)(ti0 + ty * 4 + r) * CCH + tj0 + tx * 4 + c2] = 0.f;
        return;
    }
    __shared__ float Qs[16][68];
    __shared__ float Ks[16][68];
    size_t tbase = (size_t)b * T_ + (size_t)c * CCH;
    float acc[4][4] = {};
    for (int e0 = 0; e0 < E_; e0 += 16) {
        int e_l = tid & 15, row0 = tid >> 4;
        #pragma unroll
        for (int r = 0; r < 4; ++r) {
            int row = row0 + 16 * r;
            Qs[e_l][row] = q[(tbase + ti0 + row) * E_ + e0 + e_l];
            Ks[e_l][row] = k[(tbase + tj0 + row) * E_ + e0 + e_l];
        }
        __syncthreads();
        #pragma unroll
        for (int kk = 0; kk < 16; ++kk) {
            float a[4], bb[4];
            #pragma unroll
            for (int r = 0; r < 4; ++r) a[r] = Qs[kk][ty * 4 + r];
            #pragma unroll
            for (int c2 = 0; c2 < 4; ++c2) bb[c2] = Ks[kk][tx * 4 + c2];
            #pragma unroll
            for (int r = 0; r < 4; ++r)
                #pragma unroll
                for (int c2 = 0; c2 < 4; ++c2) acc[r][c2] += a[r] * bb[c2];
        }
        __syncthreads();
    }
    #pragma unroll
    for (int r = 0; r < 4; ++r) {
        int row = ti0 + ty * 4 + r;
        #pragma unroll
        for (int c2 = 0; c2 < 4; ++c2) {
            int col = tj0 + tx * 4 + c2;
            Pp[(size_t)row * CCH + col] = (col <= row) ? acc[r][c2] : 0.f;
        }
    }
}

// ---------------------------------------------------------------------------
// Kernel 7: denominator.  d[b,t] = max(q_t . z_prev + rowsum(P_t), EPS); store 1/d
// ---------------------------------------------------------------------------
__global__ void denom_kernel(const float* __restrict__ q, const float* __restrict__ z,
                             const float* __restrict__ P, float* __restrict__ invd) {
    __shared__ float red[256];
    int row = blockIdx.x;            // b*T + t
    int b = row / T_, t = row % T_;
    int c = t / CCH, tl = t % CCH;
    const float* qr = q + (size_t)row * E_;
    const float* zr = z + ((size_t)b * NC_ + c) * E_;
    const float* Pr = P + (((size_t)b * NC_ + c) * CCH + tl) * CCH;
    int tid = threadIdx.x;
    float s = qr[tid] * zr[tid] + qr[tid + 256] * zr[tid + 256] + Pr[tid];
    red[tid] = s;
    __syncthreads();
    for (int st = 128; st > 0; st >>= 1) {
        if (tid < st) red[tid] += red[tid + st];
        __syncthreads();
    }
    if (tid == 0) invd[row] = 1.f / fmaxf(red[0], EPS_);
}

// ---------------------------------------------------------------------------
// Kernel 8: attn[b,t,i] = (q_t @ S_prev[c] + P_t @ V_c)[i] * invd[b,t]
// ---------------------------------------------------------------------------
__global__ void attnout_kernel(const float* __restrict__ q, const float* __restrict__ S,
                               const float* __restrict__ P, const float* __restrict__ v,
                               const float* __restrict__ invd, float* __restrict__ attn) {
    __shared__ float Ls[16][68];   // transposed operand (q rows / P rows)
    __shared__ float Rs[16][64];   // straight operand (S / V)
    int tid = threadIdx.x;
    int tx = tid & 15, ty = tid >> 4;
    int t0 = blockIdx.x * 64;
    int i0 = blockIdx.y * 64;
    int b  = blockIdx.z;
    int c = t0 / CCH, tl0 = t0 % CCH;
    float acc[4][4] = {};
    // part 1: q @ S_prev, K = 512
    const float* Sp = S + ((size_t)b * NC_ + c) * E_ * E_;
    for (int e0 = 0; e0 < E_; e0 += 16) {
        {
            int e_l = tid & 15, row0 = tid >> 4;
            #pragma unroll
            for (int r = 0; r < 4; ++r) {
                int row = row0 + 16 * r;
                Ls[e_l][row] = q[((size_t)b * T_ + t0 + row) * E_ + e0 + e_l];
            }
        }
        {
            int jj = tid & 63, el0 = tid >> 6;
            #pragma unroll
            for (int r = 0; r < 4; ++r) {
                int e_l = el0 + 4 * r;
                Rs[e_l][jj] = Sp[(size_t)(e0 + e_l) * E_ + i0 + jj];
            }
        }
        __syncthreads();
        #pragma unroll
        for (int kk = 0; kk < 16; ++kk) {
            float a[4], bb[4];
            #pragma unroll
            for (int r = 0; r < 4; ++r) a[r] = Ls[kk][ty * 4 + r];
            #pragma unroll
            for (int c2 = 0; c2 < 4; ++c2) bb[c2] = Rs[kk][tx * 4 + c2];
            #pragma unroll
            for (int r = 0; r < 4; ++r)
                #pragma unroll
                for (int c2 = 0; c2 < 4; ++c2) acc[r][c2] += a[r] * bb[c2];
        }
        __syncthreads();
    }
    // part 2: P @ V, K = CCH
    const float* Pp = P + ((size_t)b * NC_ + c) * CCH * CCH;
    for (int j0 = 0; j0 < CCH; j0 += 16) {
        {
            int j_l = tid & 15, row0 = tid >> 4;
            #pragma unroll
            for (int r = 0; r < 4; ++r) {
                int row = row0 + 16 * r;
                Ls[j_l][row] = Pp[(size_t)(tl0 + row) * CCH + j0 + j_l];
            }
        }
        {
            int jj = tid & 63, jl0 = tid >> 6;
            #pragma unroll
            for (int r = 0; r < 4; ++r) {
                int j_l = jl0 + 4 * r;
                Rs[j_l][jj] = v[((size_t)b * T_ + c * CCH + j0 + j_l) * E_ + i0 + jj];
            }
        }
        __syncthreads();
        #pragma unroll
        for (int kk = 0; kk < 16; ++kk) {
            float a[4], bb[4];
            #pragma unroll
            for (int r = 0; r < 4; ++r) a[r] = Ls[kk][ty * 4 + r];
            #pragma unroll
            for (int c2 = 0; c2 < 4; ++c2) bb[c2] = Rs[kk][tx * 4 + c2];
            #pragma unroll
            for (int r = 0; r < 4; ++r)
                #pragma unroll
                for (int c2 = 0; c2 < 4; ++c2) acc[r][c2] += a[r] * bb[c2];
        }
        __syncthreads();
    }
    #pragma unroll
    for (int r = 0; r < 4; ++r) {
        int t = t0 + ty * 4 + r;
        float sc = invd[(size_t)b * T_ + t];
        #pragma unroll
        for (int c2 = 0; c2 < 4; ++c2)
            attn[((size_t)b * T_ + t) * E_ + i0 + tx * 4 + c2] = acc[r][c2] * sc;
    }
}

// ---------------------------------------------------------------------------
// Kernel 9: out[b,t,i] = sum_e attn[b,t,e] * o_w[i,e] + o_b[i]
// ---------------------------------------------------------------------------
__global__ void outproj_kernel(const float* __restrict__ attn, const float* __restrict__ W,
                               const float* __restrict__ bias, float* __restrict__ out) {
    __shared__ float As[16][68];
    __shared__ float Ws[16][68];
    int tid = threadIdx.x;
    int tx = tid & 15, ty = tid >> 4;
    int t0 = blockIdx.x * 64;
    int i0 = blockIdx.y * 64;
    int b  = blockIdx.z;
    float acc[4][4] = {};
    for (int e0 = 0; e0 < E_; e0 += 16) {
        {
            int e_l = tid & 15, row0 = tid >> 4;
            #pragma unroll
            for (int r = 0; r < 4; ++r) {
                int row = row0 + 16 * r;
                As[e_l][row] = attn[((size_t)b * T_ + t0 + row) * E_ + e0 + e_l];
            }
        }
        {
            int e_l = tid & 15, il0 = tid >> 4;
            #pragma unroll
            for (int r = 0; r < 4; ++r) {
                int i_l = il0 + 16 * r;
                Ws[e_l][i_l] = W[(size_t)(i0 + i_l) * E_ + e0 + e_l];
            }
        }
        __syncthreads();
        #pragma unroll
        for (int kk = 0; kk < 16; ++kk) {
            float a[4], bb[4];
            #pragma unroll
            for (int r = 0; r < 4; ++r) a[r] = As[kk][ty * 4 + r];
            #pragma unroll
            for (int c2 = 0; c2 < 4; ++c2) bb[c2] = Ws[kk][tx * 4 + c2];
            #pragma unroll
            for (int r = 0; r < 4; ++r)
                #pragma unroll
                for (int c2 = 0; c2 < 4; ++c2) acc[r][c2] += a[r] * bb[c2];
        }
        __syncthreads();
    }
    #pragma unroll
    for (int r = 0; r < 4; ++r) {
        int t = t0 + ty * 4 + r;
        #pragma unroll
        for (int c2 = 0; c2 < 4; ++c2) {
            int i = i0 + tx * 4 + c2;
            out[((size_t)b * T_ + t) * E_ + i] = acc[r][c2] + bias[i];
        }
    }
}

// ---------------------------------------------------------------------------
extern "C" void kernel_launch(void* const* d_in, const int* in_sizes, int n_in,
                              void* d_out, int out_size, void* d_ws, size_t ws_size,
                              hipStream_t stream) {
    const float* x    = (const float*)d_in[0];
    const float* toep = (const float*)d_in[1];
    const float* q_w  = (const float*)d_in[2];
    const float* q_b  = (const float*)d_in[3];
    const float* k_w  = (const float*)d_in[4];
    const float* k_b  = (const float*)d_in[5];
    const float* v_w  = (const float*)d_in[6];
    const float* v_b  = (const float*)d_in[7];
    const float* o_w  = (const float*)d_in[8];
    const float* o_b  = (const float*)d_in[9];

    float* ws = (float*)d_ws;
    const size_t NTE = (size_t)B_ * T_ * E_;        // 8388608
    float* q    = ws;
    float* k    = q + NTE;
    float* v    = k + NTE;
    float* KV   = v + NTE;                          // B*NC*E*E = 16777216
    float* ksum = KV + (size_t)B_ * NC_ * E_ * E_;  // 32768
    float* P    = ksum + (size_t)B_ * NC_ * E_;     // B*NC*C*C = 4194304
    float* invd = P + (size_t)B_ * NC_ * CCH * CCH; // 16384
    float* attn = k;                                // k dead after pmat/ksum: reuse
    float* out  = (float*)d_out;

    dim3 blk(256);
    dim3 gproj(T_ / 64, E_ / 64, B_);
    proj_kernel<<<gproj, blk, 0, stream>>>(x, q_w, q_b, toep, q, 0);
    proj_kernel<<<gproj, blk, 0, stream>>>(x, k_w, k_b, toep, k, 1);
    proj_kernel<<<gproj, blk, 0, stream>>>(x, v_w, v_b, toep, v, 2);
    softmax_kernel<<<dim3(B_ * T_), blk, 0, stream>>>(q);
    chunk_kv_kernel<<<dim3(E_ / 64, E_ / 64, B_ * NC_), blk, 0, stream>>>(k, v, KV);
    ksum_kernel<<<dim3(B_ * NC_, E_ / 256), blk, 0, stream>>>(k, ksum);
    scan_kernel<<<dim3((B_ * E_ * E_) / 256), blk, 0, stream>>>(KV, (size_t)E_ * E_);
    scan_kernel<<<dim3((B_ * E_) / 256), blk, 0, stream>>>(ksum, (size_t)E_);
    pmat_kernel<<<dim3(CCH / 64, CCH / 64, B_ * NC_), blk, 0, stream>>>(q, k, P);
    denom_kernel<<<dim3(B_ * T_), blk, 0, stream>>>(q, ksum, P, invd);
    attnout_kernel<<<dim3(T_ / 64, E_ / 64, B_), blk, 0, stream>>>(q, KV, P, v, invd, attn);
    outproj_kernel<<<dim3(T_ / 64, E_ / 64, B_), blk, 0, stream>>>(attn, o_w, o_b, out);
}

// Round 3
// 296.380 us; speedup vs baseline: 3.3895x; 3.3895x over previous
//
#include <hip/hip_runtime.h>
#include <hip/hip_bf16.h>
#include <math.h>
#include <stdint.h>

#define B_ 8
#define T_ 2048
#define E_ 512
#define CCH 256
#define NC_ 8
#define EPS_ 1e-3f
#define QSCALE 0.044194173824159216f   // 512^-0.5

typedef __attribute__((ext_vector_type(8))) short short8;
typedef __attribute__((ext_vector_type(4))) float f32x4;
typedef __hip_bfloat16 bf16_t;

__device__ __forceinline__ short f2bs(float x) {
    bf16_t h = __float2bfloat16(x);
    return __builtin_bit_cast(short, h);
}

// async global->LDS, 16B per lane; LDS dest is wave-uniform base + lane*16
__device__ __forceinline__ void async16(const void* g, void* l) {
    __builtin_amdgcn_global_load_lds(
        (const __attribute__((address_space(1))) unsigned int*)(unsigned long long)(uintptr_t)g,
        (__attribute__((address_space(3))) unsigned int*)(unsigned int)(uintptr_t)l,
        16, 0, 0);
}

// ---------------------------------------------------------------------------
// Shared GEMM core: C[128x128] += A[128xK] * (B^T[128xK])^T, bf16 in, fp32 acc.
// Both operands stored row-major with K contiguous. 256 threads = 4 waves 2x2,
// each wave 64x64 = 4x4 MFMA 16x16x32 tiles. BK=32.
// ---------------------------------------------------------------------------
__device__ __forceinline__ void gemm128(const short* __restrict__ Ag, int lda,
                                        const short* __restrict__ Bg, int ldb, int K,
                                        short* Al, short* Bl, f32x4 acc[4][4],
                                        int wm, int wn, int wq, int lane) {
    int m16 = lane & 15, quad = lane >> 4;
    for (int k0 = 0; k0 < K; k0 += 32) {
        __syncthreads();
        #pragma unroll
        for (int cc = 0; cc < 2; ++cc) {
            int row = wq * 32 + cc * 16 + (lane >> 2);
            int kc = (lane & 3) * 8;
            async16(Ag + (size_t)row * lda + k0 + kc, Al + (wq * 32 + cc * 16) * 32);
            async16(Bg + (size_t)row * ldb + k0 + kc, Bl + (wq * 32 + cc * 16) * 32);
        }
        __syncthreads();
        short8 a[4], b[4];
        #pragma unroll
        for (int i = 0; i < 4; ++i)
            a[i] = *(const short8*)(Al + (wm + i * 16 + m16) * 32 + quad * 8);
        #pragma unroll
        for (int i = 0; i < 4; ++i)
            b[i] = *(const short8*)(Bl + (wn + i * 16 + m16) * 32 + quad * 8);
        #pragma unroll
        for (int i = 0; i < 4; ++i)
            #pragma unroll
            for (int j = 0; j < 4; ++j)
                acc[i][j] = __builtin_amdgcn_mfma_f32_16x16x32_bf16(a[i], b[j], acc[i][j], 0, 0, 0);
    }
}

#define GEMM_PROLOG \
    int tid = threadIdx.x, lane = tid & 63, wq = tid >> 6; \
    int wm = (wq & 1) * 64, wn = (wq >> 1) * 64; \
    int m16 = lane & 15, quad = lane >> 4; \
    (void)tid; \
    f32x4 acc[4][4]; \
    { f32x4 zz = {0.f, 0.f, 0.f, 0.f}; \
      for (int i = 0; i < 4; ++i) for (int j = 0; j < 4; ++j) acc[i][j] = zz; }

// ---------------------------------------------------------------------------
__global__ void castw_kernel(const float* __restrict__ qw, const float* __restrict__ kw,
                             const float* __restrict__ vw, const float* __restrict__ ow,
                             short* __restrict__ wbf) {
    size_t idx8 = ((size_t)blockIdx.x * 256 + threadIdx.x) * 8;
    int sel = (int)(idx8 >> 18);
    size_t off = idx8 & ((1u << 18) - 1);
    const float* src = sel == 0 ? qw : sel == 1 ? kw : sel == 2 ? vw : ow;
    const float4* sp = (const float4*)(src + off);
    float4 a = sp[0], b = sp[1];
    short8 g;
    g[0] = f2bs(a.x); g[1] = f2bs(a.y); g[2] = f2bs(a.z); g[3] = f2bs(a.w);
    g[4] = f2bs(b.x); g[5] = f2bs(b.y); g[6] = f2bs(b.z); g[7] = f2bs(b.w);
    *(short8*)(wbf + idx8) = g;
}

// ---------------------------------------------------------------------------
__global__ void transpose_x_kernel(const float* __restrict__ x, short* __restrict__ xbf) {
    __shared__ __align__(16) float S[64][68];
    int tid = threadIdx.x;
    int t0 = blockIdx.x * 64, e0 = blockIdx.y * 64, b = blockIdx.z;
    const float* src = x + ((size_t)b * E_ + e0) * T_ + t0;
    short* dst = xbf + ((size_t)b * T_ + t0) * E_ + e0;
    #pragma unroll
    for (int p = 0; p < 2; ++p) {
        int el = p * 32 + (tid >> 3), tc = (tid & 7) * 8;
        const float4* sp = (const float4*)(src + (size_t)el * T_ + tc);
        *(float4*)&S[el][tc] = sp[0];
        *(float4*)&S[el][tc + 4] = sp[1];
    }
    __syncthreads();
    #pragma unroll
    for (int p = 0; p < 2; ++p) {
        int tl = p * 32 + (tid >> 3), ec = (tid & 7) * 8;
        short8 g;
        #pragma unroll
        for (int j = 0; j < 8; ++j) g[j] = f2bs(S[ec + j][tl]);
        *(short8*)(dst + (size_t)tl * E_ + ec) = g;
    }
}

// ---------------------------------------------------------------------------
__global__ void transpose_bf_kernel(const short* __restrict__ k, const short* __restrict__ v,
                                    short* __restrict__ kT, short* __restrict__ vT) {
    __shared__ __align__(16) short S[64][72];
    int tid = threadIdx.x;
    int t0 = blockIdx.x * 64, e0 = blockIdx.y * 64;
    int b = blockIdx.z >> 1, which = blockIdx.z & 1;
    const short* src = (which ? v : k) + ((size_t)b * T_ + t0) * E_ + e0;
    short* dst = (which ? vT : kT) + ((size_t)b * E_ + e0) * T_ + t0;
    #pragma unroll
    for (int p = 0; p < 2; ++p) {
        int tl = p * 32 + (tid >> 3), ec = (tid & 7) * 8;
        *(short8*)&S[tl][ec] = *(const short8*)(src + (size_t)tl * E_ + ec);
    }
    __syncthreads();
    #pragma unroll
    for (int p = 0; p < 2; ++p) {
        int er = p * 32 + (tid >> 3), tc = (tid & 7) * 8;
        short8 g;
        #pragma unroll
        for (int j = 0; j < 8; ++j) g[j] = S[tc + j][er];
        *(short8*)(dst + (size_t)er * T_ + tc) = g;
    }
}

// ---------------------------------------------------------------------------
__global__ __launch_bounds__(256) void proj_qkv_kernel(
    const short* __restrict__ xbf, const short* __restrict__ wbf,
    const float* __restrict__ qb, const float* __restrict__ kb, const float* __restrict__ vb,
    const float* __restrict__ toep,
    float* __restrict__ qf, bf16_t* __restrict__ kout, bf16_t* __restrict__ vout) {
    __shared__ __align__(16) short Al[128 * 32], Bl[128 * 32];
    GEMM_PROLOG
    int t0 = blockIdx.x * 128, i0 = blockIdx.y * 128;
    int b = blockIdx.z / 3, sel = blockIdx.z % 3;
    const short* Ag = xbf + ((size_t)b * T_ + t0) * E_;
    const short* Bg = wbf + (size_t)sel * E_ * E_ + (size_t)i0 * E_;
    gemm128(Ag, E_, Bg, E_, E_, Al, Bl, acc, wm, wn, wq, lane);
    const float* bias = (sel == 0) ? qb : (sel == 1) ? kb : vb;
    #pragma unroll
    for (int mt = 0; mt < 4; ++mt)
        #pragma unroll
        for (int r = 0; r < 4; ++r) {
            int t = t0 + wm + mt * 16 + quad * 4 + r;
            size_t rowoff = ((size_t)b * T_ + t) * E_;
            float tw = toep[t];
            #pragma unroll
            for (int nt = 0; nt < 4; ++nt) {
                int col = i0 + wn + nt * 16 + m16;
                float vv = acc[mt][nt][r] + bias[col];
                if (sel == 0) qf[rowoff + col] = vv;
                else if (sel == 1) kout[rowoff + col] = __float2bfloat16(expf(vv));
                else vout[rowoff + col] = __float2bfloat16(vv * tw);
            }
        }
}

// ---------------------------------------------------------------------------
__global__ void softmax_kernel(const float* __restrict__ qf, bf16_t* __restrict__ qbf) {
    __shared__ float red[256];
    int row = blockIdx.x, tid = threadIdx.x;
    const float* p = qf + (size_t)row * E_;
    float v0 = p[tid], v1 = p[tid + 256];
    red[tid] = fmaxf(v0, v1);
    __syncthreads();
    for (int s = 128; s > 0; s >>= 1) { if (tid < s) red[tid] = fmaxf(red[tid], red[tid + s]); __syncthreads(); }
    float m = red[0];
    __syncthreads();
    float e0 = expf(v0 - m), e1 = expf(v1 - m);
    red[tid] = e0 + e1;
    __syncthreads();
    for (int s = 128; s > 0; s >>= 1) { if (tid < s) red[tid] += red[tid + s]; __syncthreads(); }
    float inv = QSCALE / red[0];
    qbf[(size_t)row * E_ + tid] = __float2bfloat16(e0 * inv);
    qbf[(size_t)row * E_ + tid + 256] = __float2bfloat16(e1 * inv);
}

// ---------------------------------------------------------------------------
__global__ __launch_bounds__(256) void chunk_kv_kernel(
    const short* __restrict__ vT, const short* __restrict__ kT, bf16_t* __restrict__ KV) {
    __shared__ __align__(16) short Al[128 * 32], Bl[128 * 32];
    GEMM_PROLOG
    int ev0 = blockIdx.x * 128, ek0 = blockIdx.y * 128;
    int bc = blockIdx.z, b = bc >> 3, c = bc & 7;
    const short* Ag = vT + ((size_t)b * E_ + ev0) * T_ + c * CCH;
    const short* Bg = kT + ((size_t)b * E_ + ek0) * T_ + c * CCH;
    gemm128(Ag, T_, Bg, T_, CCH, Al, Bl, acc, wm, wn, wq, lane);
    #pragma unroll
    for (int mt = 0; mt < 4; ++mt)
        #pragma unroll
        for (int r = 0; r < 4; ++r) {
            int ev = ev0 + wm + mt * 16 + quad * 4 + r;
            #pragma unroll
            for (int nt = 0; nt < 4; ++nt) {
                int ek = ek0 + wn + nt * 16 + m16;
                KV[((size_t)bc * E_ + ev) * E_ + ek] = __float2bfloat16(acc[mt][nt][r]);
            }
        }
}

// ---------------------------------------------------------------------------
__global__ void scan_kv_kernel(bf16_t* __restrict__ KV) {
    size_t gid = (size_t)blockIdx.x * 256 + threadIdx.x;
    size_t b = gid >> 18, idx = gid & ((1u << 18) - 1);
    bf16_t* p = KV + b * ((size_t)NC_ * E_ * E_) + idx;
    float run = 0.f;
    for (int c = 0; c < NC_; ++c) {
        float t = __bfloat162float(*p);
        *p = __float2bfloat16(run);
        run += t;
        p += (size_t)E_ * E_;
    }
}

// ---------------------------------------------------------------------------
__global__ void ksum_kernel(const bf16_t* __restrict__ k, float* __restrict__ ks) {
    int bc = blockIdx.x, b = bc >> 3, c = bc & 7;
    int e = blockIdx.y * 256 + threadIdx.x;
    const bf16_t* kp = k + ((size_t)b * T_ + (size_t)c * CCH) * E_ + e;
    float s = 0.f;
    for (int t = 0; t < CCH; ++t) s += __bfloat162float(kp[(size_t)t * E_]);
    ks[(size_t)bc * E_ + e] = s;
}
__global__ void scan_f_kernel(float* __restrict__ buf, int nper) {
    int gid = blockIdx.x * 256 + threadIdx.x;
    int b = gid / nper, idx = gid % nper;
    float run = 0.f;
    float* p = buf + (size_t)b * NC_ * nper + idx;
    for (int c = 0; c < NC_; ++c) { float t = *p; *p = run; run += t; p += nper; }
}

// ---------------------------------------------------------------------------
__global__ __launch_bounds__(256) void pmat_kernel(
    const short* __restrict__ qbf, const short* __restrict__ kbf, bf16_t* __restrict__ P) {
    __shared__ __align__(16) short Al[128 * 32], Bl[128 * 32];
    int tj0 = blockIdx.x * 128, ti0 = blockIdx.y * 128;
    int bc = blockIdx.z, b = bc >> 3, c = bc & 7;
    short* Pp = (short*)P + (size_t)bc * CCH * CCH;
    if (tj0 > ti0) {           // fully above diagonal: zero-fill (ws is poisoned)
        short8 z8 = {0, 0, 0, 0, 0, 0, 0, 0};
        for (int i = threadIdx.x; i < 128 * 128 / 8; i += 256) {
            int row = i >> 4, colc = (i * 8) & 127;
            *(short8*)(Pp + (size_t)(ti0 + row) * CCH + tj0 + colc) = z8;
        }
        return;
    }
    GEMM_PROLOG
    const short* Ag = qbf + ((size_t)b * T_ + c * CCH + ti0) * E_;
    const short* Bg = kbf + ((size_t)b * T_ + c * CCH + tj0) * E_;
    gemm128(Ag, E_, Bg, E_, E_, Al, Bl, acc, wm, wn, wq, lane);
    #pragma unroll
    for (int mt = 0; mt < 4; ++mt)
        #pragma unroll
        for (int r = 0; r < 4; ++r) {
            int row = ti0 + wm + mt * 16 + quad * 4 + r;
            #pragma unroll
            for (int nt = 0; nt < 4; ++nt) {
                int col = tj0 + wn + nt * 16 + m16;
                float vv = (col <= row) ? acc[mt][nt][r] : 0.f;
                ((bf16_t*)Pp)[(size_t)row * CCH + col] = __float2bfloat16(vv);
            }
        }
}

// ---------------------------------------------------------------------------
__global__ void denom_kernel(const bf16_t* __restrict__ qbf, const float* __restrict__ z,
                             const bf16_t* __restrict__ P, float* __restrict__ invd) {
    __shared__ float red[256];
    int row = blockIdx.x, tid = threadIdx.x;
    int b = row >> 11, t = row & (T_ - 1);
    int c = t >> 8, tl = t & 255;
    const bf16_t* qr = qbf + (size_t)row * E_;
    const float* zr = z + ((size_t)(b * NC_ + c)) * E_;
    const bf16_t* Pr = P + (((size_t)(b * NC_ + c)) * CCH + tl) * CCH;
    float s = __bfloat162float(qr[tid]) * zr[tid]
            + __bfloat162float(qr[tid + 256]) * zr[tid + 256]
            + __bfloat162float(Pr[tid]);
    red[tid] = s;
    __syncthreads();
    for (int st = 128; st > 0; st >>= 1) { if (tid < st) red[tid] += red[tid + st]; __syncthreads(); }
    if (tid == 0) invd[row] = 1.f / fmaxf(red[0], EPS_);
}

// ---------------------------------------------------------------------------
__global__ __launch_bounds__(256) void attnout_kernel(
    const short* __restrict__ qbf, const short* __restrict__ KV,
    const short* __restrict__ P, const short* __restrict__ vT,
    const float* __restrict__ invd, bf16_t* __restrict__ attn) {
    __shared__ __align__(16) short Al[128 * 32], Bl[128 * 32];
    GEMM_PROLOG
    int t0 = blockIdx.x * 128, i0 = blockIdx.y * 128, b = blockIdx.z;
    int c = t0 >> 8, tl0 = t0 & 255, bc = b * NC_ + c;
    gemm128(qbf + ((size_t)b * T_ + t0) * E_, E_,
            KV + ((size_t)bc * E_ + i0) * E_, E_, E_, Al, Bl, acc, wm, wn, wq, lane);
    gemm128(P + ((size_t)bc * CCH + tl0) * CCH, CCH,
            vT + ((size_t)b * E_ + i0) * T_ + c * CCH, T_, CCH, Al, Bl, acc, wm, wn, wq, lane);
    #pragma unroll
    for (int mt = 0; mt < 4; ++mt)
        #pragma unroll
        for (int r = 0; r < 4; ++r) {
            int t = t0 + wm + mt * 16 + quad * 4 + r;
            float sc = invd[(size_t)b * T_ + t];
            #pragma unroll
            for (int nt = 0; nt < 4; ++nt) {
                int col = i0 + wn + nt * 16 + m16;
                attn[((size_t)b * T_ + t) * E_ + col] = __float2bfloat16(acc[mt][nt][r] * sc);
            }
        }
}

// ---------------------------------------------------------------------------
__global__ __launch_bounds__(256) void outproj_kernel(
    const short* __restrict__ attn, const short* __restrict__ wbf_o,
    const float* __restrict__ ob, float* __restrict__ out) {
    __shared__ __align__(16) short Al[128 * 32], Bl[128 * 32];
    GEMM_PROLOG
    int t0 = blockIdx.x * 128, i0 = blockIdx.y * 128, b = blockIdx.z;
    gemm128(attn + ((size_t)b * T_ + t0) * E_, E_,
            wbf_o + (size_t)i0 * E_, E_, E_, Al, Bl, acc, wm, wn, wq, lane);
    #pragma unroll
    for (int mt = 0; mt < 4; ++mt)
        #pragma unroll
        for (int r = 0; r < 4; ++r) {
            int t = t0 + wm + mt * 16 + quad * 4 + r;
            #pragma unroll
            for (int nt = 0; nt < 4; ++nt) {
                int col = i0 + wn + nt * 16 + m16;
                out[((size_t)b * T_ + t) * E_ + col] = acc[mt][nt][r] + ob[col];
            }
        }
}

// ---------------------------------------------------------------------------
extern "C" void kernel_launch(void* const* d_in, const int* in_sizes, int n_in,
                              void* d_out, int out_size, void* d_ws, size_t ws_size,
                              hipStream_t stream) {
    const float* x    = (const float*)d_in[0];
    const float* toep = (const float*)d_in[1];
    const float* q_w  = (const float*)d_in[2];
    const float* q_b  = (const float*)d_in[3];
    const float* k_w  = (const float*)d_in[4];
    const float* k_b  = (const float*)d_in[5];
    const float* v_w  = (const float*)d_in[6];
    const float* v_b  = (const float*)d_in[7];
    const float* o_w  = (const float*)d_in[8];
    const float* o_b  = (const float*)d_in[9];

    const size_t NTE = (size_t)B_ * T_ * E_;          // 8388608
    char* base = (char*)d_ws;
    short* xbf  = (short*)base;  base += NTE * 2;
    short* wbf  = (short*)base;  base += (size_t)4 * E_ * E_ * 2;
    short* qbf  = (short*)base;  base += NTE * 2;
    short* kbf  = (short*)base;  base += NTE * 2;
    short* vbf  = (short*)base;  base += NTE * 2;
    short* kT   = (short*)base;  base += NTE * 2;
    short* vT   = (short*)base;  base += NTE * 2;
    short* KV   = (short*)base;  base += (size_t)B_ * NC_ * E_ * E_ * 2;
    short* P    = (short*)base;  base += (size_t)B_ * NC_ * CCH * CCH * 2;
    float* ksum = (float*)base;  base += (size_t)B_ * NC_ * E_ * 4;
    float* invd = (float*)base;  base += (size_t)B_ * T_ * 4;
    float* qf   = (float*)base;  base += NTE * 4;
    short* attn = xbf;           // xbf dead after proj_qkv: reuse for attn bf16
    float* out  = (float*)d_out;

    dim3 blk(256);
    castw_kernel<<<dim3(512), blk, 0, stream>>>(q_w, k_w, v_w, o_w, wbf);
    transpose_x_kernel<<<dim3(32, 8, 8), blk, 0, stream>>>(x, xbf);
    proj_qkv_kernel<<<dim3(16, 4, 24), blk, 0, stream>>>(
        xbf, wbf, q_b, k_b, v_b, toep, qf, (bf16_t*)kbf, (bf16_t*)vbf);
    softmax_kernel<<<dim3(B_ * T_), blk, 0, stream>>>(qf, (bf16_t*)qbf);
    transpose_bf_kernel<<<dim3(32, 8, 16), blk, 0, stream>>>(kbf, vbf, kT, vT);
    chunk_kv_kernel<<<dim3(4, 4, 64), blk, 0, stream>>>(vT, kT, (bf16_t*)KV);
    scan_kv_kernel<<<dim3(8192), blk, 0, stream>>>((bf16_t*)KV);
    ksum_kernel<<<dim3(64, 2), blk, 0, stream>>>((const bf16_t*)kbf, ksum);
    scan_f_kernel<<<dim3(16), blk, 0, stream>>>(ksum, E_);
    pmat_kernel<<<dim3(2, 2, 64), blk, 0, stream>>>(qbf, kbf, (bf16_t*)P);
    denom_kernel<<<dim3(B_ * T_), blk, 0, stream>>>(
        (const bf16_t*)qbf, ksum, (const bf16_t*)P, invd);
    attnout_kernel<<<dim3(16, 4, 8), blk, 0, stream>>>(
        qbf, KV, P, vT, invd, (bf16_t*)attn);
    outproj_kernel<<<dim3(16, 4, 8), blk, 0, stream>>>(
        attn, wbf + (size_t)3 * E_ * E_, o_b, out);
}